// Round 7
// baseline (130.073 us; speedup 1.0000x reference)
//
#include <hip/hip_runtime.h>
#include <hip/hip_bf16.h>

#define N_SUPPORT 32768
#define N_QUERY   16384
#define DIM       512
#define NCLS      32
#define NU        128
#define NBLK      (N_SUPPORT / 256)   // 128 histogram blocks

// workspace byte offsets (all 128B aligned)
#define OFF_IDX      0         // int[32768]
#define OFF_COUNT    131072    // int[32]
#define OFF_START    131200    // int[33]
#define OFF_M        131456    // float[32]
#define OFF_Z        131584    // float[32]
#define OFF_P2       131712    // float[32]
#define OFF_LOGIT    132096    // float[32768]
#define OFF_PRAW     263168    // float[32*512]
#define OFF_PROTO    328704    // float[32*512]
#define OFF_BHIST    394240    // int[128*32]
#define OFF_BOFFS    410624    // int[128*32]
#define OFF_VBF      458752    // short[32*128*512] bf16 precast V (4 MB)

typedef __attribute__((ext_vector_type(8))) short short8;
typedef __attribute__((ext_vector_type(4))) short short4v;
typedef __attribute__((ext_vector_type(4))) float f32x4;

__device__ inline unsigned short f2bf(float f) {   // RNE f32 -> bf16
    unsigned int x = __builtin_bit_cast(unsigned int, f);
    unsigned int r = x + 0x7fffu + ((x >> 16) & 1u);
    return (unsigned short)(r >> 16);
}

__device__ inline short8 pack_bf8(float4 f0, float4 f1) {
    short8 pk;
    pk[0] = f2bf(f0.x); pk[1] = f2bf(f0.y); pk[2] = f2bf(f0.z); pk[3] = f2bf(f0.w);
    pk[4] = f2bf(f1.x); pk[5] = f2bf(f1.y); pk[6] = f2bf(f1.z); pk[7] = f2bf(f1.w);
    return pk;
}

// precast V to bf16 (once) + zero praw. 524288 float4-units over 2048 blocks.
__global__ void k_vcast(const float* __restrict__ V, short* __restrict__ Vbf,
                        float* __restrict__ praw) {
    int i = blockIdx.x * 256 + threadIdx.x;
    float4 f = *(const float4*)(V + (size_t)i * 4);
    short4v o;
    o[0] = f2bf(f.x); o[1] = f2bf(f.y); o[2] = f2bf(f.z); o[3] = f2bf(f.w);
    *(short4v*)(Vbf + (size_t)i * 4) = o;
    if (i < (NCLS * DIM) / 4) *(float4*)(praw + i * 4) = make_float4(0.f, 0.f, 0.f, 0.f);
}

// phase A: per-block class histogram
__global__ void k_hist(const int* __restrict__ labels, int* __restrict__ bhist) {
    __shared__ int h[NCLS];
    int tid = threadIdx.x;
    if (tid < NCLS) h[tid] = 0;
    __syncthreads();
    int n = blockIdx.x * 256 + tid;
    atomicAdd(&h[labels[n]], 1);
    __syncthreads();
    if (tid < NCLS) bhist[blockIdx.x * NCLS + tid] = h[tid];
}

// phase B: single block. boffs[b][k] = sum_{b'<b} bhist[b'][k]; start/count per class.
__global__ void k_scan2(const int* __restrict__ bhist, int* __restrict__ boffs,
                        int* __restrict__ start, int* __restrict__ count) {
    __shared__ int tot[NCLS];
    int tid = threadIdx.x;
    if (tid < NCLS) {
        int s = 0;
        for (int b = 0; b < NBLK; b++) {
            boffs[b * NCLS + tid] = s;
            s += bhist[b * NCLS + tid];
        }
        tot[tid] = s;
    }
    __syncthreads();
    if (tid == 0) {
        int run = 0;
        for (int k = 0; k < NCLS; k++) {
            start[k] = run;
            count[k] = tot[k];
            run += tot[k];
        }
        start[NCLS] = run;
    }
}

// phase C: stable scatter. rank within wave via per-class ballot; across waves via LDS hist.
__global__ void k_scatter(const int* __restrict__ labels, const int* __restrict__ boffs,
                          const int* __restrict__ start, int* __restrict__ idx_c) {
    __shared__ int whist[4][NCLS];
    int tid = threadIdx.x;
    int n = blockIdx.x * 256 + tid;
    int l = labels[n];
    int lane = tid & 63, wid = tid >> 6;
    unsigned long long mymask = 0ull;
    #pragma unroll
    for (int k = 0; k < NCLS; k++) {
        unsigned long long mk = __ballot(l == k);
        if (k == l) mymask = mk;
        if (lane == k) whist[wid][k] = __popcll(mk);
    }
    int rank = __popcll(mymask & ((1ull << lane) - 1ull));
    __syncthreads();
    int wbase = 0;
    for (int w = 0; w < wid; w++) wbase += whist[w][l];
    idx_c[start[l] + boffs[blockIdx.x * NCLS + l] + wbase + rank] = n;
}

// per-class MFMA GEMM, V-resident halves: P = X(128x512).V^T(512x128) bf16/f32acc,
// logit[n] = sum_u tanh(P[n,u]) * w[k,u].
// 512 threads (8 waves), TILE=128 samples/block. K in 2 halves of 256:
// stage V[128][256]+X[128][256] bf16 (XOR-swizzled, <=2-way conflicts) -> 64 MFMAs
// per wave between barriers; half-1 globals prefetched into regs under half-0 MFMAs.
// Only 4 barriers/block (round-6 had 16 + per-chunk V re-conversion).
__launch_bounds__(512, 2)
__global__ void k_logits(const float* __restrict__ support, const short* __restrict__ Vbf,
                         const float* __restrict__ w, const int* __restrict__ idx_c,
                         const int* __restrict__ start, const int* __restrict__ count,
                         float* __restrict__ logit_c) {
    int k = blockIdx.y;
    int cnt = count[k];
    int base = blockIdx.x * 128;
    if (base >= cnt) return;
    int M = min(128, cnt - base);
    int s0 = start[k] + base;
    int t = threadIdx.x;

    __shared__ __align__(16) short Vs[128 * 256];   // 64 KB
    __shared__ __align__(16) short Xs[128 * 256];   // 64 KB
    __shared__ float part[8][128];                  // 4 KB

    int l = t & 63, wv = t >> 6;
    int lo16 = l & 15, hi4 = l >> 4;
    int srow = t >> 5, sslot = t & 31;              // staging: row srow+16j, 16B slot sslot
    int sxor = (sslot ^ (srow & 7)) * 8;            // swizzled short-offset within row

    // support row indices for the 8 rows this thread stages
    int ridx[8];
    #pragma unroll
    for (int j = 0; j < 8; j++) {
        int r = srow + 16 * j;
        ridx[j] = idx_c[s0 + ((r < M) ? r : 0)];
    }
    const short* Vk = Vbf + (size_t)k * NU * DIM;

    f32x4 acc[4][2];
    #pragma unroll
    for (int sub = 0; sub < 4; sub++)
        #pragma unroll
        for (int mt = 0; mt < 2; mt++) acc[sub][mt] = (f32x4){0.f, 0.f, 0.f, 0.f};

    float4 xf[8][2];
    short8 vf[8];
    // prologue: load half 0 into regs
    #pragma unroll
    for (int j = 0; j < 8; j++) {
        int r = srow + 16 * j;
        const float* xp = support + (size_t)ridx[j] * DIM + sslot * 8;
        xf[j][0] = *(const float4*)xp;
        xf[j][1] = *(const float4*)(xp + 4);
        vf[j] = *(const short8*)(Vk + (size_t)r * DIM + sslot * 8);
    }

    int vrow = wv * 16 + lo16;
    #pragma unroll
    for (int kh = 0; kh < 2; kh++) {
        // write staged regs to LDS (convert X f32->bf16)
        #pragma unroll
        for (int j = 0; j < 8; j++) {
            int r = srow + 16 * j;
            *(short8*)&Xs[r * 256 + sxor] = pack_bf8(xf[j][0], xf[j][1]);
            *(short8*)&Vs[r * 256 + sxor] = vf[j];
        }
        __syncthreads();
        if (kh == 0) {   // issue half-1 global loads; land under the MFMAs below
            #pragma unroll
            for (int j = 0; j < 8; j++) {
                int r = srow + 16 * j;
                const float* xp = support + (size_t)ridx[j] * DIM + 256 + sslot * 8;
                xf[j][0] = *(const float4*)xp;
                xf[j][1] = *(const float4*)(xp + 4);
                vf[j] = *(const short8*)(Vk + (size_t)r * DIM + 256 + sslot * 8);
            }
        }
        #pragma unroll
        for (int ks = 0; ks < 8; ks++) {
            int sw = ((ks * 4 + hi4) ^ (lo16 & 7)) * 8;
            short8 b = *(short8*)&Vs[vrow * 256 + sw];
            #pragma unroll
            for (int sub = 0; sub < 4; sub++)
                #pragma unroll
                for (int mt = 0; mt < 2; mt++) {
                    short8 a = *(short8*)&Xs[(sub * 32 + mt * 16 + lo16) * 256 + sw];
                    acc[sub][mt] = __builtin_amdgcn_mfma_f32_16x16x32_bf16(a, b, acc[sub][mt], 0, 0, 0);
                }
        }
        if (kh == 0) __syncthreads();   // half-0 fragment reads done before overwrite
    }

    // epilogue: tanh * w, reduce over this wave's 16 u-cols, then across 8 waves.
    // D layout: row=(l>>4)*4+r, col=l&15 (verified rounds 5/6).
    float wval = w[k * NU + wv * 16 + lo16];
    #pragma unroll
    for (int sub = 0; sub < 4; sub++)
        #pragma unroll
        for (int mt = 0; mt < 2; mt++)
            #pragma unroll
            for (int r = 0; r < 4; r++) {
                float val = tanhf(acc[sub][mt][r]) * wval;
                val += __shfl_xor(val, 1);
                val += __shfl_xor(val, 2);
                val += __shfl_xor(val, 4);
                val += __shfl_xor(val, 8);
                if (lo16 == 0) part[wv][sub * 32 + mt * 16 + hi4 * 4 + r] = val;
            }
    __syncthreads();
    if (t < 128 && t < M) {
        float s = 0.f;
        #pragma unroll
        for (int wq = 0; wq < 8; wq++) s += part[wq][t];
        logit_c[s0 + t] = s;
    }
}

// per-class max and sum-exp (deterministic tree reduce)
__global__ void k_mz(const float* __restrict__ logit_c, const int* __restrict__ start,
                     const int* __restrict__ count, float* __restrict__ m, float* __restrict__ Z) {
    int k = blockIdx.x;
    int cnt = count[k], s0 = start[k];
    int tid = threadIdx.x;
    __shared__ float red[256];
    float mx = -1e30f;
    for (int i = tid; i < cnt; i += 256) mx = fmaxf(mx, logit_c[s0 + i]);
    red[tid] = mx; __syncthreads();
    for (int off = 128; off > 0; off >>= 1) {
        if (tid < off) red[tid] = fmaxf(red[tid], red[tid + off]);
        __syncthreads();
    }
    float mk = red[0];
    __syncthreads();
    float s = 0.f;
    for (int i = tid; i < cnt; i += 256) s += expf(logit_c[s0 + i] - mk);
    red[tid] = s; __syncthreads();
    for (int off = 128; off > 0; off >>= 1) {
        if (tid < off) red[tid] += red[tid + off];
        __syncthreads();
    }
    if (tid == 0) { m[k] = mk; Z[k] = red[0]; }
}

// weighted prototype accumulation (unnormalized), atomics across sample-tiles
__launch_bounds__(512)
__global__ void k_proto(const float* __restrict__ support, const int* __restrict__ idx_c,
                        const float* __restrict__ logit_c, const int* __restrict__ start,
                        const int* __restrict__ count, const float* __restrict__ m,
                        float* __restrict__ praw) {
    int k = blockIdx.y;
    int cnt = count[k];
    int base = blockIdx.x * 128;
    if (base >= cnt) return;
    int M = min(128, cnt - base);
    int s0 = start[k] + base;
    float mk = m[k];
    int d = threadIdx.x;
    float a = 0.f;
    #pragma unroll 2
    for (int s = 0; s < M; s++) {
        int n = idx_c[s0 + s];
        float wt = expf(logit_c[s0 + s] - mk);
        a += wt * support[(size_t)n * DIM + d];
    }
    atomicAdd(&praw[k * DIM + d], a);
}

// normalize by Z, empty-class mean fallback, compute p2 = |proto|^2
__global__ void k_protonorm(const float* __restrict__ support, const float* __restrict__ praw,
                            const float* __restrict__ Z, const int* __restrict__ count,
                            float* __restrict__ proto, float* __restrict__ p2) {
    int k = blockIdx.x;
    int tid = threadIdx.x;
    int cnt = count[k];
    __shared__ float red[256];
    float acc = 0.f;
    if (cnt > 0) {
        float inv = 1.f / Z[k];
        for (int d = tid; d < DIM; d += 256) {
            float p = praw[k * DIM + d] * inv;
            proto[k * DIM + d] = p;
            acc += p * p;
        }
    } else {
        // empty class: uniform softmax over ALL support -> mean embedding
        for (int d = tid; d < DIM; d += 256) {
            float s = 0.f;
            for (int n = 0; n < N_SUPPORT; n++) s += support[(size_t)n * DIM + d];
            float p = s * (1.f / N_SUPPORT);
            proto[k * DIM + d] = p;
            acc += p * p;
        }
    }
    red[tid] = acc; __syncthreads();
    for (int off = 128; off > 0; off >>= 1) {
        if (tid < off) red[tid] += red[tid + off];
        __syncthreads();
    }
    if (tid == 0) p2[k] = red[0];
}

// distances + log_softmax. 32 queries/block (512 blocks), 8 class-groups of 4,
// register prefetch of next D-chunk. q2 cancels in log_softmax.
__launch_bounds__(256, 1)
__global__ void k_dist(const float* __restrict__ query, const float* __restrict__ proto,
                       const float* __restrict__ p2, float* __restrict__ out) {
    __shared__ float Qs[32][68];
    __shared__ float Ps[32][68];
    __shared__ float Ls[32][33];
    __shared__ float mlse[32];
    int tid = threadIdx.x;
    int qbase = blockIdx.x * 32;
    int lq = tid & 31, g = tid >> 5;   // g in 0..7 -> classes g*4..g*4+3
    float acc[4];
    #pragma unroll
    for (int a = 0; a < 4; a++) acc[a] = 0.f;

    // staging mapping: 32 rows x 16 float4-slots = 512 units, 2/thread
    int r0 = tid >> 4, sl = tid & 15;   // unit rep: rows r0, r0+16

    float4 qv[2], pv[2];
    #pragma unroll
    for (int rep = 0; rep < 2; rep++) {
        int r = r0 + 16 * rep;
        qv[rep] = *(const float4*)(query + (size_t)(qbase + r) * DIM + sl * 4);
        pv[rep] = *(const float4*)(proto + (size_t)r * DIM + sl * 4);
    }

    for (int dc = 0; dc < DIM; dc += 64) {
        if (dc) __syncthreads();
        #pragma unroll
        for (int rep = 0; rep < 2; rep++) {
            int r = r0 + 16 * rep;
            *(float4*)&Qs[r][sl * 4] = qv[rep];
            *(float4*)&Ps[r][sl * 4] = pv[rep];
        }
        __syncthreads();
        if (dc + 64 < DIM) {
            #pragma unroll
            for (int rep = 0; rep < 2; rep++) {
                int r = r0 + 16 * rep;
                qv[rep] = *(const float4*)(query + (size_t)(qbase + r) * DIM + dc + 64 + sl * 4);
                pv[rep] = *(const float4*)(proto + (size_t)r * DIM + dc + 64 + sl * 4);
            }
        }
        #pragma unroll
        for (int d4 = 0; d4 < 16; d4++) {
            float4 q4 = *(const float4*)&Qs[lq][d4 * 4];
            #pragma unroll
            for (int c = 0; c < 4; c++) {
                float4 p4 = *(const float4*)&Ps[g * 4 + c][d4 * 4];
                acc[c] += q4.x * p4.x + q4.y * p4.y + q4.z * p4.z + q4.w * p4.w;
            }
        }
    }
    #pragma unroll
    for (int c = 0; c < 4; c++)
        Ls[lq][g * 4 + c] = 2.f * acc[c] - p2[g * 4 + c];
    __syncthreads();
    if (tid < 32) {
        float mx = -1e30f;
        #pragma unroll
        for (int k = 0; k < 32; k++) mx = fmaxf(mx, Ls[tid][k]);
        float s = 0.f;
        #pragma unroll
        for (int k = 0; k < 32; k++) s += expf(Ls[tid][k] - mx);
        mlse[tid] = mx + logf(s);
    }
    __syncthreads();
    #pragma unroll
    for (int c = 0; c < 4; c++)
        out[(size_t)(qbase + lq) * NCLS + g * 4 + c] = Ls[lq][g * 4 + c] - mlse[lq];
}

extern "C" void kernel_launch(void* const* d_in, const int* in_sizes, int n_in,
                              void* d_out, int out_size, void* d_ws, size_t ws_size,
                              hipStream_t stream) {
    const float* query   = (const float*)d_in[0];
    const float* support = (const float*)d_in[1];
    const int*   labels  = (const int*)d_in[2];
    const float* V       = (const float*)d_in[3];
    const float* w       = (const float*)d_in[4];
    float* out = (float*)d_out;
    char* ws = (char*)d_ws;

    int*   idx_c   = (int*)(ws + OFF_IDX);
    int*   count   = (int*)(ws + OFF_COUNT);
    int*   start   = (int*)(ws + OFF_START);
    float* m       = (float*)(ws + OFF_M);
    float* Z       = (float*)(ws + OFF_Z);
    float* p2      = (float*)(ws + OFF_P2);
    float* logit_c = (float*)(ws + OFF_LOGIT);
    float* praw    = (float*)(ws + OFF_PRAW);
    float* proto   = (float*)(ws + OFF_PROTO);
    int*   bhist   = (int*)(ws + OFF_BHIST);
    int*   boffs   = (int*)(ws + OFF_BOFFS);
    short* vbf     = (short*)(ws + OFF_VBF);

    hipLaunchKernelGGL(k_vcast, dim3((NCLS * NU * DIM) / 1024), dim3(256), 0, stream, V, vbf, praw);
    hipLaunchKernelGGL(k_hist, dim3(NBLK), dim3(256), 0, stream, labels, bhist);
    hipLaunchKernelGGL(k_scan2, dim3(1), dim3(64), 0, stream, bhist, boffs, start, count);
    hipLaunchKernelGGL(k_scatter, dim3(NBLK), dim3(256), 0, stream, labels, boffs, start, idx_c);
    // 16 tiles of 128 covers counts up to 2048 (expected ~1024 +/- 31 for uniform labels)
    hipLaunchKernelGGL(k_logits, dim3(16, NCLS), dim3(512), 0, stream,
                       support, vbf, w, idx_c, start, count, logit_c);
    hipLaunchKernelGGL(k_mz, dim3(NCLS), dim3(256), 0, stream, logit_c, start, count, m, Z);
    hipLaunchKernelGGL(k_proto, dim3(32, NCLS), dim3(512), 0, stream,
                       support, idx_c, logit_c, start, count, m, praw);
    hipLaunchKernelGGL(k_protonorm, dim3(NCLS), dim3(256), 0, stream,
                       support, praw, Z, count, proto, p2);
    hipLaunchKernelGGL(k_dist, dim3(N_QUERY / 32), dim3(256), 0, stream, query, proto, p2, out);
}

// Round 8
// 101.917 us; speedup vs baseline: 1.2763x; 1.2763x over previous
//
#include <hip/hip_runtime.h>
#include <hip/hip_bf16.h>

#define N_SUPPORT 32768
#define N_QUERY   16384
#define DIM       512
#define NCLS      32
#define NU        128
#define NBLK      (N_SUPPORT / 256)   // 128 histogram blocks

// workspace byte offsets (all 128B aligned)
#define OFF_IDX      0         // int[32768]
#define OFF_COUNT    131072    // int[32]
#define OFF_START    131200    // int[33]
#define OFF_M        131456    // float[32]
#define OFF_Z        131584    // float[32]
#define OFF_P2       131712    // float[32]
#define OFF_LOGIT    132096    // float[32768]
#define OFF_PRAW     263168    // float[32*512]
#define OFF_PROTO    328704    // float[32*512]
#define OFF_BHIST    394240    // int[128*32]
#define OFF_BOFFS    410624    // int[128*32]
#define OFF_VBF      458752    // short[32*8*128*64] bf16 V, chunked+swizzled (4 MB)

typedef __attribute__((ext_vector_type(8))) short short8;
typedef __attribute__((ext_vector_type(4))) short short4v;
typedef __attribute__((ext_vector_type(4))) float f32x4;

__device__ inline unsigned short f2bf(float f) {   // RNE f32 -> bf16
    unsigned int x = __builtin_bit_cast(unsigned int, f);
    unsigned int r = x + 0x7fffu + ((x >> 16) & 1u);
    return (unsigned short)(r >> 16);
}

__device__ inline short8 pack_bf8(float4 f0, float4 f1) {
    short8 pk;
    pk[0] = f2bf(f0.x); pk[1] = f2bf(f0.y); pk[2] = f2bf(f0.z); pk[3] = f2bf(f0.w);
    pk[4] = f2bf(f1.x); pk[5] = f2bf(f1.y); pk[6] = f2bf(f1.z); pk[7] = f2bf(f1.w);
    return pk;
}

// precast V to bf16 in the chunked+swizzled layout k_logits' LDS wants:
// Vbf[((k*8 + c)*128 + u)*64 + s*8 + j] = bf16(V[k][u][c*64 + (s^(u&7))*8 + j])
// so k_logits V staging is a pure linear short8 copy. Also zero praw.
__global__ void k_vcast(const float* __restrict__ V, short* __restrict__ Vbf,
                        float* __restrict__ praw) {
    int i = blockIdx.x * 256 + threadIdx.x;
    int ob = i * 4;                       // output short offset (4 shorts/thread)
    int j0  = ob & 7;                     // 0 or 4
    int s   = (ob >> 3) & 7;
    int u   = (ob >> 6) & 127;
    int c   = (ob >> 13) & 7;
    int k   = ob >> 16;
    int d   = c * 64 + ((s ^ (u & 7)) * 8) + j0;
    float4 f = *(const float4*)(V + ((size_t)(k * 128 + u) * DIM + d));
    short4v o;
    o[0] = f2bf(f.x); o[1] = f2bf(f.y); o[2] = f2bf(f.z); o[3] = f2bf(f.w);
    *(short4v*)(Vbf + (size_t)ob) = o;
    if (i < (NCLS * DIM) / 4) *(float4*)(praw + i * 4) = make_float4(0.f, 0.f, 0.f, 0.f);
}

// phase A: per-block class histogram
__global__ void k_hist(const int* __restrict__ labels, int* __restrict__ bhist) {
    __shared__ int h[NCLS];
    int tid = threadIdx.x;
    if (tid < NCLS) h[tid] = 0;
    __syncthreads();
    int n = blockIdx.x * 256 + tid;
    atomicAdd(&h[labels[n]], 1);
    __syncthreads();
    if (tid < NCLS) bhist[blockIdx.x * NCLS + tid] = h[tid];
}

// phase B: single block. boffs[b][k] = sum_{b'<b} bhist[b'][k]; start/count per class.
__global__ void k_scan2(const int* __restrict__ bhist, int* __restrict__ boffs,
                        int* __restrict__ start, int* __restrict__ count) {
    __shared__ int tot[NCLS];
    int tid = threadIdx.x;
    if (tid < NCLS) {
        int s = 0;
        for (int b = 0; b < NBLK; b++) {
            boffs[b * NCLS + tid] = s;
            s += bhist[b * NCLS + tid];
        }
        tot[tid] = s;
    }
    __syncthreads();
    if (tid == 0) {
        int run = 0;
        for (int k = 0; k < NCLS; k++) {
            start[k] = run;
            count[k] = tot[k];
            run += tot[k];
        }
        start[NCLS] = run;
    }
}

// phase C: stable scatter. rank within wave via per-class ballot; across waves via LDS hist.
__global__ void k_scatter(const int* __restrict__ labels, const int* __restrict__ boffs,
                          const int* __restrict__ start, int* __restrict__ idx_c) {
    __shared__ int whist[4][NCLS];
    int tid = threadIdx.x;
    int n = blockIdx.x * 256 + tid;
    int l = labels[n];
    int lane = tid & 63, wid = tid >> 6;
    unsigned long long mymask = 0ull;
    #pragma unroll
    for (int k = 0; k < NCLS; k++) {
        unsigned long long mk = __ballot(l == k);
        if (k == l) mymask = mk;
        if (lane == k) whist[wid][k] = __popcll(mk);
    }
    int rank = __popcll(mymask & ((1ull << lane) - 1ull));
    __syncthreads();
    int wbase = 0;
    for (int w = 0; w < wid; w++) wbase += whist[w][l];
    idx_c[start[l] + boffs[blockIdx.x * NCLS + l] + wbase + rank] = n;
}

// per-class MFMA GEMM (R6 structure + precast V + LDS double-buffer):
// P = X(32x512).V^T(512x128) bf16/f32acc; logit[n] = sum_u tanh(P[n,u])*w[k,u].
// M=32 tile, 256 thr (4 waves), 9 barriers/block (1/chunk), V staging = pure
// short8 copy from pre-swizzled Vbf (no f2bf, coalesced 1KB/wave), X converts
// f32->bf16 in-flight. LDS 40.7KB -> 3 blocks/CU.
__launch_bounds__(256, 1)
__global__ void k_logits(const float* __restrict__ support, const short* __restrict__ Vbf,
                         const float* __restrict__ w, const int* __restrict__ idx_c,
                         const int* __restrict__ start, const int* __restrict__ count,
                         float* __restrict__ logit_c) {
    int k = blockIdx.y;
    int cnt = count[k];
    int base = blockIdx.x * 32;
    if (base >= cnt) return;
    int M = min(32, cnt - base);
    int s0 = start[k] + base;
    int t = threadIdx.x;

    __shared__ __align__(16) short Xs[2][32 * 64];    // 2 x 4 KB
    __shared__ __align__(16) short Vs[2][128 * 64];   // 2 x 16 KB
    __shared__ float part[4][32];
    __shared__ int sidx[32];
    if (t < 32) sidx[t] = idx_c[s0 + ((t < M) ? t : 0)];
    __syncthreads();

    int l = t & 63, wv = t >> 6;
    int lo16 = l & 15, hi4 = l >> 4;
    int xrow = t >> 3, xslot = t & 7;                 // X: 32 rows x 8 slots, 1 unit/thread
    int xdst = xrow * 64 + ((xslot ^ (xrow & 7)) * 8);
    const float* xsrc = support + (size_t)sidx[xrow] * DIM + xslot * 8;
    const short* Vkc = Vbf + (size_t)k * (8 * 128 * 64);   // chunk c at +c*8192

    f32x4 acc[2][2];
    #pragma unroll
    for (int mt = 0; mt < 2; mt++)
        #pragma unroll
        for (int nt = 0; nt < 2; nt++) acc[mt][nt] = (f32x4){0.f, 0.f, 0.f, 0.f};

    float4 xv0, xv1;
    short8 vf[4];

    // prologue: load + stage chunk 0
    xv0 = *(const float4*)(xsrc);
    xv1 = *(const float4*)(xsrc + 4);
    #pragma unroll
    for (int rep = 0; rep < 4; rep++)
        vf[rep] = *(const short8*)(Vkc + (size_t)(t + 256 * rep) * 8);
    *(short8*)&Xs[0][xdst] = pack_bf8(xv0, xv1);
    #pragma unroll
    for (int rep = 0; rep < 4; rep++)
        *(short8*)&Vs[0][(t + 256 * rep) * 8] = vf[rep];

    int vrow0 = wv * 32 + lo16;
    for (int c = 0; c < 8; ++c) {
        int cur = c & 1;
        __syncthreads();                    // buf[cur] visible (drains everything)
        if (c < 7) {                        // issue next-chunk loads under MFMAs
            xv0 = *(const float4*)(xsrc + (c + 1) * 64);
            xv1 = *(const float4*)(xsrc + (c + 1) * 64 + 4);
            #pragma unroll
            for (int rep = 0; rep < 4; rep++)
                vf[rep] = *(const short8*)(Vkc + (size_t)(c + 1) * 8192 + (size_t)(t + 256 * rep) * 8);
        }
        #pragma unroll
        for (int ks = 0; ks < 2; ks++) {
            short8 a[2], b[2];
            #pragma unroll
            for (int mt = 0; mt < 2; mt++) {
                int ar = mt * 16 + lo16;
                a[mt] = *(short8*)&Xs[cur][ar * 64 + (((ks * 4 + hi4) ^ (ar & 7)) * 8)];
            }
            #pragma unroll
            for (int nt = 0; nt < 2; nt++) {
                int vr = vrow0 + nt * 16;
                b[nt] = *(short8*)&Vs[cur][vr * 64 + (((ks * 4 + hi4) ^ (vr & 7)) * 8)];
            }
            #pragma unroll
            for (int mt = 0; mt < 2; mt++)
                #pragma unroll
                for (int nt = 0; nt < 2; nt++)
                    acc[mt][nt] = __builtin_amdgcn_mfma_f32_16x16x32_bf16(a[mt], b[nt], acc[mt][nt], 0, 0, 0);
        }
        if (c < 7) {                        // write next buffer (other half: safe)
            int nxt = cur ^ 1;
            *(short8*)&Xs[nxt][xdst] = pack_bf8(xv0, xv1);
            #pragma unroll
            for (int rep = 0; rep < 4; rep++)
                *(short8*)&Vs[nxt][(t + 256 * rep) * 8] = vf[rep];
        }
    }

    // epilogue: tanh * w, reduce over u. D layout: row=(l>>4)*4+r, col=l&15.
    float w0 = w[k * NU + wv * 32 + lo16];
    float w1 = w[k * NU + wv * 32 + 16 + lo16];
    #pragma unroll
    for (int mt = 0; mt < 2; mt++) {
        #pragma unroll
        for (int r = 0; r < 4; r++) {
            float val = tanhf(acc[mt][0][r]) * w0 + tanhf(acc[mt][1][r]) * w1;
            val += __shfl_xor(val, 1);
            val += __shfl_xor(val, 2);
            val += __shfl_xor(val, 4);
            val += __shfl_xor(val, 8);
            if (lo16 == 0) part[wv][mt * 16 + hi4 * 4 + r] = val;
        }
    }
    __syncthreads();
    if (t < M) {
        logit_c[s0 + t] = part[0][t] + part[1][t] + part[2][t] + part[3][t];
    }
}

// per-class max and sum-exp (deterministic tree reduce)
__global__ void k_mz(const float* __restrict__ logit_c, const int* __restrict__ start,
                     const int* __restrict__ count, float* __restrict__ m, float* __restrict__ Z) {
    int k = blockIdx.x;
    int cnt = count[k], s0 = start[k];
    int tid = threadIdx.x;
    __shared__ float red[256];
    float mx = -1e30f;
    for (int i = tid; i < cnt; i += 256) mx = fmaxf(mx, logit_c[s0 + i]);
    red[tid] = mx; __syncthreads();
    for (int off = 128; off > 0; off >>= 1) {
        if (tid < off) red[tid] = fmaxf(red[tid], red[tid + off]);
        __syncthreads();
    }
    float mk = red[0];
    __syncthreads();
    float s = 0.f;
    for (int i = tid; i < cnt; i += 256) s += expf(logit_c[s0 + i] - mk);
    red[tid] = s; __syncthreads();
    for (int off = 128; off > 0; off >>= 1) {
        if (tid < off) red[tid] += red[tid + off];
        __syncthreads();
    }
    if (tid == 0) { m[k] = mk; Z[k] = red[0]; }
}

// weighted prototype accumulation: weights+indices staged once in LDS (kills
// 512x-redundant exp), 4-row explicit load pipeline, tile 64 -> 512 active blocks.
__launch_bounds__(512, 1)
__global__ void k_proto(const float* __restrict__ support, const int* __restrict__ idx_c,
                        const float* __restrict__ logit_c, const int* __restrict__ start,
                        const int* __restrict__ count, const float* __restrict__ m,
                        float* __restrict__ praw) {
    int k = blockIdx.y;
    int cnt = count[k];
    int base = blockIdx.x * 64;
    if (base >= cnt) return;
    int M = min(64, cnt - base);
    int s0 = start[k] + base;
    __shared__ float wts[64];
    __shared__ int sid[64];
    int t = threadIdx.x;
    if (t < 64) {
        sid[t] = idx_c[s0 + ((t < M) ? t : 0)];
        wts[t] = (t < M) ? expf(logit_c[s0 + t] - m[k]) : 0.f;
    }
    __syncthreads();
    int d = t;
    float a = 0.f;
    for (int s = 0; s < 64; s += 4) {
        float r0 = support[(size_t)sid[s + 0] * DIM + d];
        float r1 = support[(size_t)sid[s + 1] * DIM + d];
        float r2 = support[(size_t)sid[s + 2] * DIM + d];
        float r3 = support[(size_t)sid[s + 3] * DIM + d];
        a += wts[s] * r0 + wts[s + 1] * r1 + wts[s + 2] * r2 + wts[s + 3] * r3;
    }
    atomicAdd(&praw[k * DIM + d], a);
}

// normalize by Z, empty-class mean fallback, compute p2 = |proto|^2
__global__ void k_protonorm(const float* __restrict__ support, const float* __restrict__ praw,
                            const float* __restrict__ Z, const int* __restrict__ count,
                            float* __restrict__ proto, float* __restrict__ p2) {
    int k = blockIdx.x;
    int tid = threadIdx.x;
    int cnt = count[k];
    __shared__ float red[256];
    float acc = 0.f;
    if (cnt > 0) {
        float inv = 1.f / Z[k];
        for (int d = tid; d < DIM; d += 256) {
            float p = praw[k * DIM + d] * inv;
            proto[k * DIM + d] = p;
            acc += p * p;
        }
    } else {
        // empty class: uniform softmax over ALL support -> mean embedding
        for (int d = tid; d < DIM; d += 256) {
            float s = 0.f;
            for (int n = 0; n < N_SUPPORT; n++) s += support[(size_t)n * DIM + d];
            float p = s * (1.f / N_SUPPORT);
            proto[k * DIM + d] = p;
            acc += p * p;
        }
    }
    red[tid] = acc; __syncthreads();
    for (int off = 128; off > 0; off >>= 1) {
        if (tid < off) red[tid] += red[tid + off];
        __syncthreads();
    }
    if (tid == 0) p2[k] = red[0];
}

// distances + log_softmax, proto-resident: protos staged ONCE (66 KB f32),
// 64 q/block x 256 blocks (exactly 1/CU, 8 waves), Q double-buffered,
// 1 barrier per 64-dim chunk, reg prefetch under compute. q2 cancels.
__launch_bounds__(512, 1)
__global__ void k_dist(const float* __restrict__ query, const float* __restrict__ proto,
                       const float* __restrict__ p2, float* __restrict__ out) {
    __shared__ float Pf[32 * 516];      // protos, pad 516
    __shared__ float Qs[2][64 * 68];    // Q chunk double buffer
    __shared__ float Ls[64 * 33];
    __shared__ float mlse[64];
    int tid = threadIdx.x;
    int qbase = blockIdx.x * 64;
    int lq = tid & 63, g = tid >> 6;    // g in 0..7 -> classes g*4..g*4+3

    // stage all protos once: 4096 float4 units, 8/thread
    #pragma unroll
    for (int rep = 0; rep < 8; rep++) {
        int u = tid + 512 * rep;
        int r = u >> 7, c4 = u & 127;
        *(float4*)&Pf[r * 516 + c4 * 4] = *(const float4*)(proto + (size_t)r * DIM + c4 * 4);
    }

    // Q staging mapping: 1024 units (64 rows x 16 slots), 2/thread
    int qrow[2], qsl[2];
    #pragma unroll
    for (int rep = 0; rep < 2; rep++) {
        int u = tid + 512 * rep;
        qrow[rep] = u >> 4; qsl[rep] = u & 15;
    }

    float acc[4];
    #pragma unroll
    for (int a = 0; a < 4; a++) acc[a] = 0.f;

    float4 qv[2];
    #pragma unroll
    for (int rep = 0; rep < 2; rep++)
        qv[rep] = *(const float4*)(query + (size_t)(qbase + qrow[rep]) * DIM + qsl[rep] * 4);
    #pragma unroll
    for (int rep = 0; rep < 2; rep++)
        *(float4*)&Qs[0][qrow[rep] * 68 + qsl[rep] * 4] = qv[rep];

    for (int c = 0; c < 8; ++c) {
        int cur = c & 1;
        __syncthreads();                // buf[cur] (+ protos on c==0) visible
        if (c < 7) {                    // issue next chunk loads under compute
            #pragma unroll
            for (int rep = 0; rep < 2; rep++)
                qv[rep] = *(const float4*)(query + (size_t)(qbase + qrow[rep]) * DIM + (c + 1) * 64 + qsl[rep] * 4);
        }
        #pragma unroll
        for (int d4 = 0; d4 < 16; d4++) {
            float4 q4 = *(const float4*)&Qs[cur][lq * 68 + d4 * 4];
            #pragma unroll
            for (int cl = 0; cl < 4; cl++) {
                float4 p4 = *(const float4*)&Pf[(g * 4 + cl) * 516 + c * 64 + d4 * 4];
                acc[cl] += q4.x * p4.x + q4.y * p4.y + q4.z * p4.z + q4.w * p4.w;
            }
        }
        if (c < 7) {
            #pragma unroll
            for (int rep = 0; rep < 2; rep++)
                *(float4*)&Qs[cur ^ 1][qrow[rep] * 68 + qsl[rep] * 4] = qv[rep];
        }
    }

    #pragma unroll
    for (int cl = 0; cl < 4; cl++)
        Ls[lq * 33 + g * 4 + cl] = 2.f * acc[cl] - p2[g * 4 + cl];
    __syncthreads();
    if (tid < 64) {
        float mx = -1e30f;
        #pragma unroll
        for (int k = 0; k < 32; k++) mx = fmaxf(mx, Ls[tid * 33 + k]);
        float s = 0.f;
        #pragma unroll
        for (int k = 0; k < 32; k++) s += expf(Ls[tid * 33 + k] - mx);
        mlse[tid] = mx + logf(s);
    }
    __syncthreads();
    #pragma unroll
    for (int cl = 0; cl < 4; cl++)
        out[(size_t)(qbase + lq) * NCLS + g * 4 + cl] = Ls[lq * 33 + g * 4 + cl] - mlse[lq];
}

extern "C" void kernel_launch(void* const* d_in, const int* in_sizes, int n_in,
                              void* d_out, int out_size, void* d_ws, size_t ws_size,
                              hipStream_t stream) {
    const float* query   = (const float*)d_in[0];
    const float* support = (const float*)d_in[1];
    const int*   labels  = (const int*)d_in[2];
    const float* V       = (const float*)d_in[3];
    const float* w       = (const float*)d_in[4];
    float* out = (float*)d_out;
    char* ws = (char*)d_ws;

    int*   idx_c   = (int*)(ws + OFF_IDX);
    int*   count   = (int*)(ws + OFF_COUNT);
    int*   start   = (int*)(ws + OFF_START);
    float* m       = (float*)(ws + OFF_M);
    float* Z       = (float*)(ws + OFF_Z);
    float* p2      = (float*)(ws + OFF_P2);
    float* logit_c = (float*)(ws + OFF_LOGIT);
    float* praw    = (float*)(ws + OFF_PRAW);
    float* proto   = (float*)(ws + OFF_PROTO);
    int*   bhist   = (int*)(ws + OFF_BHIST);
    int*   boffs   = (int*)(ws + OFF_BOFFS);
    short* vbf     = (short*)(ws + OFF_VBF);

    hipLaunchKernelGGL(k_vcast, dim3((NCLS * NU * DIM) / 1024), dim3(256), 0, stream, V, vbf, praw);
    hipLaunchKernelGGL(k_hist, dim3(NBLK), dim3(256), 0, stream, labels, bhist);
    hipLaunchKernelGGL(k_scan2, dim3(1), dim3(64), 0, stream, bhist, boffs, start, count);
    hipLaunchKernelGGL(k_scatter, dim3(NBLK), dim3(256), 0, stream, labels, boffs, start, idx_c);
    // 64 sample-tiles of 32 covers counts up to 2048 (expected ~1024 +/- 31 for uniform labels)
    hipLaunchKernelGGL(k_logits, dim3(64, NCLS), dim3(256), 0, stream,
                       support, vbf, w, idx_c, start, count, logit_c);
    hipLaunchKernelGGL(k_mz, dim3(NCLS), dim3(256), 0, stream, logit_c, start, count, m, Z);
    hipLaunchKernelGGL(k_proto, dim3(32, NCLS), dim3(512), 0, stream,
                       support, idx_c, logit_c, start, count, m, praw);
    hipLaunchKernelGGL(k_protonorm, dim3(NCLS), dim3(256), 0, stream,
                       support, praw, Z, count, proto, p2);
    hipLaunchKernelGGL(k_dist, dim3(N_QUERY / 64), dim3(512), 0, stream, query, proto, p2, out);
}